// Round 10
// baseline (174.168 us; speedup 1.0000x reference)
//
#include <hip/hip_runtime.h>
#include <stdint.h>

// B=4, S=2048, D=512, H=8, DH=64
#define QSCALE (0.125f * 1.44269504088896340736f)  // 1/sqrt(DH) * log2(e), folded into Q
#define MASKNEG (-1.442695e9f)                      // -1e9 * log2(e)

typedef unsigned short u16;
typedef unsigned int u32;
typedef __bf16 bf16x8 __attribute__((ext_vector_type(8)));
typedef float f32x4 __attribute__((ext_vector_type(4)));
typedef float f32x16 __attribute__((ext_vector_type(16)));
typedef u16 u16x8 __attribute__((ext_vector_type(8)));
typedef u32 u32x4 __attribute__((ext_vector_type(4)));

__device__ __forceinline__ u16 f2bf(float f) {
  u32 u = __float_as_uint(f);
  u += 0x7fffu + ((u >> 16) & 1u);  // RNE
  return (u16)(u >> 16);
}

__device__ __forceinline__ u32 cvtpk(float lo, float hi) {
  u32 d;
  asm("v_cvt_pk_bf16_f32 %0, %1, %2" : "=v"(d) : "v"(lo), "v"(hi));
  return d;
}

// swap: high 32 lanes of a <-> low 32 lanes of b
__device__ __forceinline__ void plswap(u32& a, u32& b) {
  asm("v_permlane32_swap_b32 %0, %1" : "+v"(a), "+v"(b));
}

__device__ __forceinline__ void gload16(const void* src, void* ldsbase) {
  __builtin_amdgcn_global_load_lds(
      (const __attribute__((address_space(1))) u32*)src,
      (__attribute__((address_space(3))) u32*)ldsbase, 16, 0, 0);
}

__device__ __forceinline__ bf16x8 cvt8(const f32x4& lo, const f32x4& hi) {
  u32x4 w;
  w[0] = cvtpk(lo[0], lo[1]);
  w[1] = cvtpk(lo[2], lo[3]);
  w[2] = cvtpk(hi[0], hi[1]);
  w[3] = cvtpk(hi[2], hi[3]);
  return __builtin_bit_cast(bf16x8, w);
}

// ------------- weight convert+transpose: f32 W[k][n] -> bf16 Wt[n][k] -------------
__global__ __launch_bounds__(256) void conv_w(const float* __restrict__ wq,
                                              const float* __restrict__ wk,
                                              const float* __restrict__ wv,
                                              const float* __restrict__ wo,
                                              u16* __restrict__ wT) {
  const float* src = (blockIdx.z == 0) ? wq : (blockIdx.z == 1) ? wk
                    : (blockIdx.z == 2) ? wv : wo;
  u16* dst = wT + (size_t)blockIdx.z * 262144;
  __shared__ float t[64][65];
  const int n0 = blockIdx.x * 64, k0 = blockIdx.y * 64;
  const int lr = threadIdx.x >> 6, lc = threadIdx.x & 63;
#pragma unroll
  for (int it = 0; it < 16; ++it) {
    const int row = it * 4 + lr;  // k offset
    t[row][lc] = src[(size_t)(k0 + row) * 512 + n0 + lc];
  }
  __syncthreads();
#pragma unroll
  for (int it = 0; it < 16; ++it) {
    const int row = it * 4 + lr;  // n offset
    dst[(size_t)(n0 + row) * 512 + k0 + lc] = f2bf(t[lc][row]);
  }
}

// ---------------- QKV projection: no-LDS, no-barrier, direct-from-cache GEMM ----------------
// Operands are cache-hot (weights 1.5 MB total; A panel 256 KB shared by the 8
// n-blocks grouped onto one XCD), so fragments are loaded straight from global
// (guide mistake #7: never LDS-stage data that L2-fits).  A is f32, converted
// to bf16 in the fragment path via v_cvt_pk_bf16_f32 (RNE).  Tile 128m x 64n,
// 4 waves (32m strip each); grid 1536 = 3z x 64m x 8n, XCD-bijective swizzle.
__global__ __launch_bounds__(256) void gemm_qkv(
    const float* __restrict__ xqf, const float* __restrict__ xkf,
    const float* __restrict__ xvf, const u16* __restrict__ wT,
    const float* __restrict__ bq, const float* __restrict__ bk,
    const float* __restrict__ bv, u16* __restrict__ qws, u16* __restrict__ kws,
    u16* __restrict__ vTw) {
  const int hw = blockIdx.x;
  const int lg = (hw & 7) * 192 + (hw >> 3);  // 1536 = 8 XCD x 192
  const int z = lg >> 9;
  const int rem = lg & 511;
  const int m0 = (rem >> 3) * 128, n0 = (rem & 7) * 64;
  const float* A = (z == 0) ? xqf : (z == 1) ? xkf : xvf;
  const u16* Bt = wT + (size_t)z * 262144;
  const float* bias = (z == 0) ? bq : (z == 1) ? bk : bv;

  const int tid = threadIdx.x;
  const int lane = tid & 63, wave = tid >> 6;
  const int h4 = lane >> 4, l15 = lane & 15;

  // fragment base pointers (per-lane): A rows m, B^T rows n, k-chunk h4*8
  const float* a0 = A + (size_t)(m0 + wave * 32 + l15) * 512 + h4 * 8;
  const float* a1 = a0 + 16 * 512;
  const u16* bp = Bt + (size_t)(n0 + l15) * 512 + h4 * 8;

  f32x4 acc[2][4] = {};
#pragma unroll 4
  for (int kt = 0; kt < 16; ++kt) {
    const int k0 = kt * 32;
    const f32x4 x0 = *(const f32x4*)(a0 + k0);
    const f32x4 x1 = *(const f32x4*)(a0 + k0 + 4);
    const f32x4 y0 = *(const f32x4*)(a1 + k0);
    const f32x4 y1 = *(const f32x4*)(a1 + k0 + 4);
    bf16x8 bv4[4];
#pragma unroll
    for (int j = 0; j < 4; ++j)
      bv4[j] = *(const bf16x8*)(bp + (size_t)j * 16 * 512 + k0);
    const bf16x8 av0 = cvt8(x0, x1);
    const bf16x8 av1 = cvt8(y0, y1);
#pragma unroll
    for (int j = 0; j < 4; ++j) {
      acc[0][j] = __builtin_amdgcn_mfma_f32_16x16x32_bf16(av0, bv4[j],
                                                          acc[0][j], 0, 0, 0);
      acc[1][j] = __builtin_amdgcn_mfma_f32_16x16x32_bf16(av1, bv4[j],
                                                          acc[1][j], 0, 0, 0);
    }
  }

  // epilogue: C col n = n0 + j*16 + l15; row m = m0 + wave*32 + i*16 + h4*4 + r
#pragma unroll
  for (int j = 0; j < 4; ++j) {
    const int n = n0 + j * 16 + l15;
    const float bn = bias[n];
    const int h = n >> 6, dh = n & 63;
#pragma unroll
    for (int i = 0; i < 2; ++i) {
#pragma unroll
      for (int r = 0; r < 4; ++r) {
        const int rg = m0 + wave * 32 + i * 16 + h4 * 4 + r;
        const int b = rg >> 11, s = rg & 2047;
        const int bh = b * 8 + h;
        const float val = acc[i][j][r] + bn;
        if (z == 0) {
          qws[((size_t)bh * 2048 + s) * 64 + dh] = f2bf(val * QSCALE);
        } else if (z == 1) {
          kws[((size_t)bh * 2048 + s) * 64 + dh] = f2bf(val);
        } else {
          vTw[((size_t)bh * 64 + dh) * 2048 + s] = f2bf(val);
        }
      }
    }
  }
}

// ---------------- flash attention: 32x32 MFMA, in-register P, counted vmcnt ----------------
// grid (32 bh, 16 qt); 512 thr = 8 waves; waves 0-3 keys [0,1024), 4-7 [1024,2048).
__global__ __launch_bounds__(512, 4) void attn_fwd(
    const u16* __restrict__ qws, const u16* __restrict__ kws,
    const u16* __restrict__ vTw, const int* __restrict__ mask,
    u16* __restrict__ attn) {
  __shared__ __align__(16) char ldsK[32768];   // [2 halves][2 bufs][64 keys][128B]
  __shared__ __align__(16) char ldsV[32768];   // [2 halves][2 bufs][64 dh][128B]
  __shared__ __align__(16) float biasLDS[2048];
  __shared__ float lShA[128];

  const int bh = blockIdx.x;
  const int qt = blockIdx.y;
  const int b = bh >> 3;
  const int tid = threadIdx.x;
  const int lane = tid & 63, wave = tid >> 6;
  const int half = wave >> 2, wl = wave & 3;
  const int l31 = lane & 31, h5 = lane >> 5;

  // mask -> additive bias (exp2 domain), once per block
  {
    const int4 m4 = *(const int4*)(mask + b * 2048 + tid * 4);
    float4 bv;
    bv.x = m4.x ? MASKNEG : 0.0f;
    bv.y = m4.y ? MASKNEG : 0.0f;
    bv.z = m4.z ? MASKNEG : 0.0f;
    bv.w = m4.w ? MASKNEG : 0.0f;
    *(float4*)(biasLDS + tid * 4) = bv;
  }
  asm volatile("s_waitcnt lgkmcnt(0)" ::: "memory");

  // Q fragments (already scaled): B-operand, col=q=l31, k = c*16 + h5*8 + j
  const u16* qrow_p = qws + ((size_t)bh * 2048 + qt * 128 + wl * 32 + l31) * 64;
  bf16x8 qb[4];
#pragma unroll
  for (int c = 0; c < 4; ++c)
    qb[c] = *(const bf16x8*)(qrow_p + c * 16 + h5 * 8);

  // hoisted addressing
  const int rowb = l31 * 128;
  int kxs[4];
#pragma unroll
  for (int c = 0; c < 4; ++c) kxs[c] = ((2 * c + h5) ^ (l31 & 7)) << 4;

  char* myK = ldsK + half * 16384;
  char* myV = ldsV + half * 16384;
  const int srow = wl * 8 + (lane >> 3);
  const int sc16 = lane & 7;

  auto stage = [&](int buf, int ktg) {
#pragma unroll
    for (int c = 0; c < 2; ++c) {
      const int row = c * 32 + srow;
      const int xc = (sc16 ^ (row & 7)) << 3;
      gload16(kws + ((size_t)bh * 2048 + ktg * 64 + row) * 64 + xc,
              myK + buf * 8192 + c * 4096 + (wl << 10));
      gload16(vTw + ((size_t)bh * 64 + row) * 2048 + ktg * 64 + xc,
              myV + buf * 8192 + c * 4096 + (wl << 10));
    }
  };

  f32x16 o0 = {}, o1 = {};
  float rsp0 = 0.f, rsp1 = 0.f, rsp2 = 0.f, rsp3 = 0.f;

  auto do_subtile = [&](const char* kb, const char* vb, const float* biasT,
                        int stByte, int c0) {
    // acc init = mask bias (broadcast b128 reads)
    f32x16 sv;
#pragma unroll
    for (int g = 0; g < 4; ++g) {
      const f32x4 bq4 = *(const f32x4*)(biasT + g * 8 + h5 * 4);
      sv[g * 4 + 0] = bq4[0];
      sv[g * 4 + 1] = bq4[1];
      sv[g * 4 + 2] = bq4[2];
      sv[g * 4 + 3] = bq4[3];
    }
    // S^T += K Q^T
    __builtin_amdgcn_s_setprio(1);
#pragma unroll
    for (int c = 0; c < 4; ++c) {
      const bf16x8 kf = *(const bf16x8*)(kb + stByte + rowb + kxs[c]);
      sv = __builtin_amdgcn_mfma_f32_32x32x16_bf16(kf, qb[c], sv, 0, 0, 0);
    }
    __builtin_amdgcn_s_setprio(0);
    // exp2 (masked keys -> exactly 0) + denom partials
    float p[16];
#pragma unroll
    for (int i = 0; i < 16; ++i) p[i] = __builtin_amdgcn_exp2f(sv[i]);
    rsp0 += p[0] + p[4] + p[8] + p[12];
    rsp1 += p[1] + p[5] + p[9] + p[13];
    rsp2 += p[2] + p[6] + p[10] + p[14];
    rsp3 += p[3] + p[7] + p[11] + p[15];
    // pack P -> PV A-frags via cvt_pk + permlane32_swap (no LDS)
    u32 paw[2][4];
#pragma unroll
    for (int lc = 0; lc < 2; ++lc) {
      u32 a1 = cvtpk(p[lc * 8 + 0], p[lc * 8 + 1]);
      u32 b1 = cvtpk(p[lc * 8 + 4], p[lc * 8 + 5]);
      u32 a2 = cvtpk(p[lc * 8 + 2], p[lc * 8 + 3]);
      u32 b2 = cvtpk(p[lc * 8 + 6], p[lc * 8 + 7]);
      plswap(a1, b1);
      plswap(a2, b2);
      paw[lc][0] = a1; paw[lc][1] = a2; paw[lc][2] = b1; paw[lc][3] = b2;
    }
    // O += P V
    __builtin_amdgcn_s_setprio(1);
#pragma unroll
    for (int lc = 0; lc < 2; ++lc) {
      u32x4 w = {paw[lc][0], paw[lc][1], paw[lc][2], paw[lc][3]};
      const bf16x8 pa = __builtin_bit_cast(bf16x8, w);
      const bf16x8 vf0 = *(const bf16x8*)(vb + rowb + kxs[c0 + lc]);
      o0 = __builtin_amdgcn_mfma_f32_32x32x16_bf16(pa, vf0, o0, 0, 0, 0);
      const bf16x8 vf1 = *(const bf16x8*)(vb + 4096 + rowb + kxs[c0 + lc]);
      o1 = __builtin_amdgcn_mfma_f32_32x32x16_bf16(pa, vf1, o1, 0, 0, 0);
    }
    __builtin_amdgcn_s_setprio(0);
  };

  stage(0, half * 16);

  for (int kt = 0; kt < 16; ++kt) {
    const int cur = kt & 1;
    const int ktg = half * 16 + kt;
    if (kt < 15) {
      stage(cur ^ 1, ktg + 1);
      asm volatile("s_waitcnt vmcnt(4)" ::: "memory");  // own prev loads done
    } else {
      asm volatile("s_waitcnt vmcnt(0)" ::: "memory");
    }
    __builtin_amdgcn_sched_barrier(0);
    __builtin_amdgcn_s_barrier();  // all waves' tile-cur data in LDS
    const char* kb = myK + cur * 8192;
    const char* vb = myV + cur * 8192;
    const float* biasT = biasLDS + ktg * 64;
    do_subtile(kb, vb, biasT, 0, 0);
    do_subtile(kb, vb, biasT + 32, 4096, 2);
    __builtin_amdgcn_sched_barrier(0);
    __builtin_amdgcn_s_barrier();  // reads done before next overwrite
  }

  // ---- denominator: lanes l and l+32 hold complementary key subsets of q=l31 ----
  float rs = (rsp0 + rsp1) + (rsp2 + rsp3);
  rs += __shfl_xor(rs, 32);

  // ---- partner merge in [reg][lane] layout (bank = lane%32 -> conflict-free) ----
  float* oSh2 = (float*)ldsK;  // [4 wl][32 reg][64 lane] f32 = 32 KB
  u16* trb = (u16*)ldsV;       // [128 q][64 col] u16 = 16 KB
  if (half == 1) {
#pragma unroll
    for (int reg = 0; reg < 16; ++reg) {
      oSh2[(wl * 32 + reg) * 64 + lane] = o0[reg];
      oSh2[(wl * 32 + 16 + reg) * 64 + lane] = o1[reg];
    }
    if (h5 == 0) lShA[wl * 32 + l31] = rs;
  }
  __syncthreads();
  if (half == 0) {
    const float ltot = rs + lShA[wl * 32 + l31];  // l for q=l31 (all lanes)
    const float linv = 1.0f / ltot;
#pragma unroll
    for (int reg = 0; reg < 16; ++reg) {
      const int q = (reg & 3) + 8 * (reg >> 2) + 4 * h5;
      const float inv = __shfl(linv, q);
      const float v0 = (o0[reg] + oSh2[(wl * 32 + reg) * 64 + lane]) * inv;
      const float v1 = (o1[reg] + oSh2[(wl * 32 + 16 + reg) * 64 + lane]) * inv;
      trb[(wl * 32 + q) * 64 + l31] = f2bf(v0);
      trb[(wl * 32 + q) * 64 + 32 + l31] = f2bf(v1);
    }
  }
  __syncthreads();
  // ---- coalesced store: 128 rows x 64 cols bf16 ----
  const int h = bh & 7;
#pragma unroll
  for (int i = 0; i < 2; ++i) {
    const int ii = tid + i * 512;
    const int row = ii >> 3;
    const int c8 = (ii & 7) * 8;
    const u16x8 vv = *(const u16x8*)(trb + row * 64 + c8);
    const int grow = b * 2048 + qt * 128 + row;
    *(u16x8*)(attn + (size_t)grow * 512 + h * 64 + c8) = vv;
  }
}

// ---------------- output projection: no-LDS direct-from-cache GEMM -> f32 ----------------
// Same structure as gemm_qkv but A (attn) is already bf16.  Tile 128m x 64n,
// grid 512 = 64m x 8n, XCD-bijective swizzle.
__global__ __launch_bounds__(256) void gemm_out(const u16* __restrict__ attn,
                                                const u16* __restrict__ woT,
                                                const float* __restrict__ bo,
                                                float* __restrict__ out) {
  const int hw = blockIdx.x;
  const int lg = (hw & 7) * 64 + (hw >> 3);  // 512 = 8 XCD x 64
  const int m0 = (lg >> 3) * 128, n0 = (lg & 7) * 64;

  const int tid = threadIdx.x;
  const int lane = tid & 63, wave = tid >> 6;
  const int h4 = lane >> 4, l15 = lane & 15;

  const u16* a0 = attn + (size_t)(m0 + wave * 32 + l15) * 512 + h4 * 8;
  const u16* a1 = a0 + 16 * 512;
  const u16* bp = woT + (size_t)(n0 + l15) * 512 + h4 * 8;

  f32x4 acc[2][4] = {};
#pragma unroll 4
  for (int kt = 0; kt < 16; ++kt) {
    const int k0 = kt * 32;
    const bf16x8 av0 = *(const bf16x8*)(a0 + k0);
    const bf16x8 av1 = *(const bf16x8*)(a1 + k0);
    bf16x8 bv4[4];
#pragma unroll
    for (int j = 0; j < 4; ++j)
      bv4[j] = *(const bf16x8*)(bp + (size_t)j * 16 * 512 + k0);
#pragma unroll
    for (int j = 0; j < 4; ++j) {
      acc[0][j] = __builtin_amdgcn_mfma_f32_16x16x32_bf16(av0, bv4[j],
                                                          acc[0][j], 0, 0, 0);
      acc[1][j] = __builtin_amdgcn_mfma_f32_16x16x32_bf16(av1, bv4[j],
                                                          acc[1][j], 0, 0, 0);
    }
  }

#pragma unroll
  for (int j = 0; j < 4; ++j) {
    const int n = n0 + j * 16 + l15;
    const float bn = bo[n];
#pragma unroll
    for (int i = 0; i < 2; ++i) {
      const int rbase = m0 + wave * 32 + i * 16 + h4 * 4;
#pragma unroll
      for (int r = 0; r < 4; ++r)
        out[(size_t)(rbase + r) * 512 + n] = acc[i][j][r] + bn;
    }
  }
}

extern "C" void kernel_launch(void* const* d_in, const int* in_sizes, int n_in,
                              void* d_out, int out_size, void* d_ws,
                              size_t ws_size, hipStream_t stream) {
  (void)in_sizes; (void)n_in; (void)out_size; (void)ws_size;
  const float* q = (const float*)d_in[0];
  const float* k = (const float*)d_in[1];
  const float* v = (const float*)d_in[2];
  const int* mask = (const int*)d_in[3];
  const float* wq = (const float*)d_in[4];
  const float* bq = (const float*)d_in[5];
  const float* wk = (const float*)d_in[6];
  const float* bk = (const float*)d_in[7];
  const float* wv = (const float*)d_in[8];
  const float* bv = (const float*)d_in[9];
  const float* wo = (const float*)d_in[10];
  const float* bo = (const float*)d_in[11];

  u16* attnb = (u16*)d_ws;        // [8192][512] bf16 attention output
  u16* wT = attnb + 4194304;      // 4 x [512][512] bf16 transposed
  u16* qws = wT + 1048576;        // [32 bh][2048][64] bf16, pre-scaled
  u16* kws = qws + 4194304;       // [32 bh][2048][64] bf16
  u16* vTw = kws + 4194304;       // [32 bh][64][2048] bf16 (transposed)
  float* out = (float*)d_out;

  conv_w<<<dim3(8, 8, 4), 256, 0, stream>>>(wq, wk, wv, wo, wT);
  gemm_qkv<<<1536, 256, 0, stream>>>(q, k, v, wT, bq, bk, bv, qws, kws, vTw);
  attn_fwd<<<dim3(32, 16), 512, 0, stream>>>(qws, kws, vTw, mask, attnb);
  gemm_out<<<512, 256, 0, stream>>>(attnb, wT + 786432, bo, out);
}

// Round 11
// 113.810 us; speedup vs baseline: 1.5303x; 1.5303x over previous
//
#include <hip/hip_runtime.h>
#include <stdint.h>

// B=4, S=2048, D=512, H=8, DH=64
#define QSCALE (0.125f * 1.44269504088896340736f)  // 1/sqrt(DH) * log2(e), folded into Q
#define MASKNEG (-1.442695e9f)                      // -1e9 * log2(e)

typedef unsigned short u16;
typedef unsigned int u32;
typedef __bf16 bf16x8 __attribute__((ext_vector_type(8)));
typedef float f32x4 __attribute__((ext_vector_type(4)));
typedef float f32x16 __attribute__((ext_vector_type(16)));
typedef u16 u16x8 __attribute__((ext_vector_type(8)));
typedef u32 u32x4 __attribute__((ext_vector_type(4)));

__device__ __forceinline__ u16 f2bf(float f) {
  u32 u = __float_as_uint(f);
  u += 0x7fffu + ((u >> 16) & 1u);  // RNE
  return (u16)(u >> 16);
}

__device__ __forceinline__ u32 cvtpk(float lo, float hi) {
  u32 d;
  asm("v_cvt_pk_bf16_f32 %0, %1, %2" : "=v"(d) : "v"(lo), "v"(hi));
  return d;
}

// swap: high 32 lanes of a <-> low 32 lanes of b
__device__ __forceinline__ void plswap(u32& a, u32& b) {
  asm("v_permlane32_swap_b32 %0, %1" : "+v"(a), "+v"(b));
}

__device__ __forceinline__ void gload16(const void* src, void* ldsbase) {
  __builtin_amdgcn_global_load_lds(
      (const __attribute__((address_space(1))) u32*)src,
      (__attribute__((address_space(3))) u32*)ldsbase, 16, 0, 0);
}

// ---------------- input convert: f32 [B,S,D] -> bf16 [8192][512] ----------------
__global__ __launch_bounds__(256) void conv_in(const float* __restrict__ q,
                                               const float* __restrict__ k,
                                               const float* __restrict__ v,
                                               u16* __restrict__ dst) {
  const float* src = (blockIdx.z == 0) ? q : (blockIdx.z == 1) ? k : v;
  u16* d = dst + (size_t)blockIdx.z * 4194304;
  size_t i = ((size_t)blockIdx.x * 256 + threadIdx.x) * 8;
  float4 a = *(const float4*)(src + i);
  float4 b = *(const float4*)(src + i + 4);
  u16x8 ov;
  ov[0] = f2bf(a.x); ov[1] = f2bf(a.y); ov[2] = f2bf(a.z); ov[3] = f2bf(a.w);
  ov[4] = f2bf(b.x); ov[5] = f2bf(b.y); ov[6] = f2bf(b.z); ov[7] = f2bf(b.w);
  *(u16x8*)(d + i) = ov;
}

// ------------- weight convert+transpose: f32 W[k][n] -> bf16 Wt[n][k] -------------
__global__ __launch_bounds__(256) void conv_w(const float* __restrict__ wq,
                                              const float* __restrict__ wk,
                                              const float* __restrict__ wv,
                                              const float* __restrict__ wo,
                                              u16* __restrict__ wT) {
  const float* src = (blockIdx.z == 0) ? wq : (blockIdx.z == 1) ? wk
                    : (blockIdx.z == 2) ? wv : wo;
  u16* dst = wT + (size_t)blockIdx.z * 262144;
  __shared__ float t[64][65];
  const int n0 = blockIdx.x * 64, k0 = blockIdx.y * 64;
  const int lr = threadIdx.x >> 6, lc = threadIdx.x & 63;
#pragma unroll
  for (int it = 0; it < 16; ++it) {
    const int row = it * 4 + lr;  // k offset
    t[row][lc] = src[(size_t)(k0 + row) * 512 + n0 + lc];
  }
  __syncthreads();
#pragma unroll
  for (int it = 0; it < 16; ++it) {
    const int row = it * 4 + lr;  // n offset
    dst[(size_t)(n0 + row) * 512 + k0 + lc] = f2bf(t[lc][row]);
  }
}

// ---------------- QKV projection: 8-phase 256x256 counted-vmcnt GEMM (T3+T4) ----------------
// BM=BN=256, BK=64, 8 waves (2M x 4N), LDS 128KB (A 2x32K + B 2x32K), 1 blk/CU.
// Per K-tile s (4 phases): phase q reads A-quadrant (4 b128) + B at q0 (8 b128);
// staging: q0/q1 -> A(s+1) halves into buf^1; q2/q3 -> B(s+2) halves into cur buf
// (B region free after q0).  vmcnt(4) once per K-tile keeps 2 half-tiles in
// flight across barriers — never drain to 0 in the main loop.
__global__ __launch_bounds__(512, 2) void gemm_qkv(
    const u16* __restrict__ xq, const u16* __restrict__ xk,
    const u16* __restrict__ xv, const u16* __restrict__ wT,
    const float* __restrict__ bq, const float* __restrict__ bk,
    const float* __restrict__ bv, u16* __restrict__ qws, u16* __restrict__ kws,
    u16* __restrict__ vTw) {
  __shared__ __align__(16) char lds[131072];
  const int hw = blockIdx.x;
  const int lg = (hw & 7) * 24 + (hw >> 3);  // 192 = 8 XCD x 24, bijective
  const int z = lg >> 6;
  const int rem = lg & 63;
  const int m0 = (rem >> 1) * 256, n0 = (rem & 1) * 256;
  const u16* A = (z == 0) ? xq : (z == 1) ? xk : xv;
  const u16* Bt = wT + (size_t)z * 262144;
  const float* bias = (z == 0) ? bq : (z == 1) ? bk : bv;

  const int tid = threadIdx.x;
  const int lane = tid & 63;
  const int wave = tid >> 6;   // 0..7
  const int wm = wave >> 2;    // 0..1 (128-row strip)
  const int wn = wave & 3;     // 0..3 (64-col strip)
  const int h4 = lane >> 4, l15 = lane & 15;
  const int lr8 = lane >> 3, lc8 = lane & 7;
  const int xorr = l15 & 7;
  const int kxc0 = ((h4) ^ xorr) << 4;
  const int kxc1 = ((4 + h4) ^ xorr) << 4;

  // A tile buf b at b*32768 (256 rows x 128B, swizzled); B at 65536 + b*32768.
  auto stageA = [&](int buf, int kt, int half) {
#pragma unroll
    for (int ii = 0; ii < 2; ++ii) {
      const int r = half * 128 + wave * 16 + ii * 8 + lr8;
      const int c16 = lc8 ^ (r & 7);
      gload16(A + (size_t)(m0 + r) * 512 + kt * 64 + c16 * 8,
              lds + buf * 32768 + (half * 128 + wave * 16 + ii * 8) * 128);
    }
  };
  auto stageB = [&](int buf, int kt, int half) {
#pragma unroll
    for (int ii = 0; ii < 2; ++ii) {
      const int r = half * 128 + wave * 16 + ii * 8 + lr8;
      const int c16 = lc8 ^ (r & 7);
      gload16(Bt + (size_t)(n0 + r) * 512 + kt * 64 + c16 * 8,
              lds + 65536 + buf * 32768 + (half * 128 + wave * 16 + ii * 8) * 128);
    }
  };

  f32x4 acc[8][4] = {};

  // prologue: A-0 + B-0 -> buf0, B-1 -> buf1 (A-1 staged during K-tile 0)
  stageA(0, 0, 0); stageA(0, 0, 1);
  stageB(0, 0, 0); stageB(0, 0, 1);
  stageB(1, 1, 0); stageB(1, 1, 1);
  asm volatile("s_waitcnt vmcnt(0)" ::: "memory");
  __builtin_amdgcn_sched_barrier(0);
  __builtin_amdgcn_s_barrier();

  for (int s = 0; s < 8; ++s) {
    const int cur = s & 1;
    const char* bA = lds + cur * 32768;
    const char* bB = lds + 65536 + cur * 32768;
    bf16x8 bvv[4][2];
#pragma unroll
    for (int q = 0; q < 4; ++q) {
      // ---- ds_read: A quadrant q (2 M-frags x 2 kk) ----
      bf16x8 av[2][2];
#pragma unroll
      for (int m = 0; m < 2; ++m) {
        const int row = wm * 128 + (2 * q + m) * 16 + l15;
        av[m][0] = *(const bf16x8*)(bA + row * 128 + kxc0);
        av[m][1] = *(const bf16x8*)(bA + row * 128 + kxc1);
      }
      // ---- B frags once per K-tile (held in regs across the 4 phases) ----
      if (q == 0) {
#pragma unroll
        for (int j = 0; j < 4; ++j) {
          const int row = wn * 64 + j * 16 + l15;
          bvv[j][0] = *(const bf16x8*)(bB + row * 128 + kxc0);
          bvv[j][1] = *(const bf16x8*)(bB + row * 128 + kxc1);
        }
      }
      // ---- staging interleave (1 half-tile per phase) ----
      if (q == 0 && s < 7) stageA(cur ^ 1, s + 1, 0);
      if (q == 1 && s < 7) stageA(cur ^ 1, s + 1, 1);
      if (q == 2 && s < 6) stageB(cur, s + 2, 0);
      if (q == 3 && s < 6) stageB(cur, s + 2, 1);
      __builtin_amdgcn_sched_barrier(0);
      __builtin_amdgcn_s_barrier();
      asm volatile("s_waitcnt lgkmcnt(0)" ::: "memory");
      __builtin_amdgcn_sched_barrier(0);
      __builtin_amdgcn_s_setprio(1);
#pragma unroll
      for (int kk = 0; kk < 2; ++kk)
#pragma unroll
        for (int m = 0; m < 2; ++m)
#pragma unroll
          for (int j = 0; j < 4; ++j)
            acc[2 * q + m][j] = __builtin_amdgcn_mfma_f32_16x16x32_bf16(
                av[m][kk], bvv[j][kk], acc[2 * q + m][j], 0, 0, 0);
      __builtin_amdgcn_s_setprio(0);
      if (q == 3) {
        if (s < 6)
          asm volatile("s_waitcnt vmcnt(4)" ::: "memory");
        else
          asm volatile("s_waitcnt vmcnt(0)" ::: "memory");
      }
      __builtin_amdgcn_sched_barrier(0);
      __builtin_amdgcn_s_barrier();
    }
  }

  // epilogue
#pragma unroll
  for (int j = 0; j < 4; ++j) {
    const int n = n0 + wn * 64 + j * 16 + l15;
    const float bn = bias[n];
    const int h = n >> 6, dh = n & 63;
#pragma unroll
    for (int mf = 0; mf < 8; ++mf) {
#pragma unroll
      for (int r = 0; r < 4; ++r) {
        const int rg = m0 + wm * 128 + mf * 16 + h4 * 4 + r;
        const int b = rg >> 11, ss = rg & 2047;
        const int bh = b * 8 + h;
        const float val = acc[mf][j][r] + bn;
        if (z == 0) {
          qws[((size_t)bh * 2048 + ss) * 64 + dh] = f2bf(val * QSCALE);
        } else if (z == 1) {
          kws[((size_t)bh * 2048 + ss) * 64 + dh] = f2bf(val);
        } else {
          vTw[((size_t)bh * 64 + dh) * 2048 + ss] = f2bf(val);
        }
      }
    }
  }
}

// ---------------- flash attention: 32x32 MFMA, in-register P, counted vmcnt ----------------
// grid (32 bh, 16 qt); 512 thr = 8 waves; waves 0-3 keys [0,1024), 4-7 [1024,2048).
__global__ __launch_bounds__(512, 4) void attn_fwd(
    const u16* __restrict__ qws, const u16* __restrict__ kws,
    const u16* __restrict__ vTw, const int* __restrict__ mask,
    u16* __restrict__ attn) {
  __shared__ __align__(16) char ldsK[32768];   // [2 halves][2 bufs][64 keys][128B]
  __shared__ __align__(16) char ldsV[32768];   // [2 halves][2 bufs][64 dh][128B]
  __shared__ __align__(16) float biasLDS[2048];
  __shared__ float lShA[128];

  const int bh = blockIdx.x;
  const int qt = blockIdx.y;
  const int b = bh >> 3;
  const int tid = threadIdx.x;
  const int lane = tid & 63, wave = tid >> 6;
  const int half = wave >> 2, wl = wave & 3;
  const int l31 = lane & 31, h5 = lane >> 5;

  // mask -> additive bias (exp2 domain), once per block
  {
    const int4 m4 = *(const int4*)(mask + b * 2048 + tid * 4);
    float4 bv;
    bv.x = m4.x ? MASKNEG : 0.0f;
    bv.y = m4.y ? MASKNEG : 0.0f;
    bv.z = m4.z ? MASKNEG : 0.0f;
    bv.w = m4.w ? MASKNEG : 0.0f;
    *(float4*)(biasLDS + tid * 4) = bv;
  }
  asm volatile("s_waitcnt lgkmcnt(0)" ::: "memory");

  // Q fragments (already scaled): B-operand, col=q=l31, k = c*16 + h5*8 + j
  const u16* qrow_p = qws + ((size_t)bh * 2048 + qt * 128 + wl * 32 + l31) * 64;
  bf16x8 qb[4];
#pragma unroll
  for (int c = 0; c < 4; ++c)
    qb[c] = *(const bf16x8*)(qrow_p + c * 16 + h5 * 8);

  // hoisted addressing
  const int rowb = l31 * 128;
  int kxs[4];
#pragma unroll
  for (int c = 0; c < 4; ++c) kxs[c] = ((2 * c + h5) ^ (l31 & 7)) << 4;

  char* myK = ldsK + half * 16384;
  char* myV = ldsV + half * 16384;
  const int srow = wl * 8 + (lane >> 3);
  const int sc16 = lane & 7;

  auto stage = [&](int buf, int ktg) {
#pragma unroll
    for (int c = 0; c < 2; ++c) {
      const int row = c * 32 + srow;
      const int xc = (sc16 ^ (row & 7)) << 3;
      gload16(kws + ((size_t)bh * 2048 + ktg * 64 + row) * 64 + xc,
              myK + buf * 8192 + c * 4096 + (wl << 10));
      gload16(vTw + ((size_t)bh * 64 + row) * 2048 + ktg * 64 + xc,
              myV + buf * 8192 + c * 4096 + (wl << 10));
    }
  };

  f32x16 o0 = {}, o1 = {};
  float rsp0 = 0.f, rsp1 = 0.f, rsp2 = 0.f, rsp3 = 0.f;

  auto do_subtile = [&](const char* kb, const char* vb, const float* biasT,
                        int stByte, int c0) {
    // acc init = mask bias (broadcast b128 reads)
    f32x16 sv;
#pragma unroll
    for (int g = 0; g < 4; ++g) {
      const f32x4 bq4 = *(const f32x4*)(biasT + g * 8 + h5 * 4);
      sv[g * 4 + 0] = bq4[0];
      sv[g * 4 + 1] = bq4[1];
      sv[g * 4 + 2] = bq4[2];
      sv[g * 4 + 3] = bq4[3];
    }
    // S^T += K Q^T
    __builtin_amdgcn_s_setprio(1);
#pragma unroll
    for (int c = 0; c < 4; ++c) {
      const bf16x8 kf = *(const bf16x8*)(kb + stByte + rowb + kxs[c]);
      sv = __builtin_amdgcn_mfma_f32_32x32x16_bf16(kf, qb[c], sv, 0, 0, 0);
    }
    __builtin_amdgcn_s_setprio(0);
    // exp2 (masked keys -> exactly 0) + denom partials
    float p[16];
#pragma unroll
    for (int i = 0; i < 16; ++i) p[i] = __builtin_amdgcn_exp2f(sv[i]);
    rsp0 += p[0] + p[4] + p[8] + p[12];
    rsp1 += p[1] + p[5] + p[9] + p[13];
    rsp2 += p[2] + p[6] + p[10] + p[14];
    rsp3 += p[3] + p[7] + p[11] + p[15];
    // pack P -> PV A-frags via cvt_pk + permlane32_swap (no LDS)
    u32 paw[2][4];
#pragma unroll
    for (int lc = 0; lc < 2; ++lc) {
      u32 a1 = cvtpk(p[lc * 8 + 0], p[lc * 8 + 1]);
      u32 b1 = cvtpk(p[lc * 8 + 4], p[lc * 8 + 5]);
      u32 a2 = cvtpk(p[lc * 8 + 2], p[lc * 8 + 3]);
      u32 b2 = cvtpk(p[lc * 8 + 6], p[lc * 8 + 7]);
      plswap(a1, b1);
      plswap(a2, b2);
      paw[lc][0] = a1; paw[lc][1] = a2; paw[lc][2] = b1; paw[lc][3] = b2;
    }
    // O += P V
    __builtin_amdgcn_s_setprio(1);
#pragma unroll
    for (int lc = 0; lc < 2; ++lc) {
      u32x4 w = {paw[lc][0], paw[lc][1], paw[lc][2], paw[lc][3]};
      const bf16x8 pa = __builtin_bit_cast(bf16x8, w);
      const bf16x8 vf0 = *(const bf16x8*)(vb + rowb + kxs[c0 + lc]);
      o0 = __builtin_amdgcn_mfma_f32_32x32x16_bf16(pa, vf0, o0, 0, 0, 0);
      const bf16x8 vf1 = *(const bf16x8*)(vb + 4096 + rowb + kxs[c0 + lc]);
      o1 = __builtin_amdgcn_mfma_f32_32x32x16_bf16(pa, vf1, o1, 0, 0, 0);
    }
    __builtin_amdgcn_s_setprio(0);
  };

  stage(0, half * 16);

  for (int kt = 0; kt < 16; ++kt) {
    const int cur = kt & 1;
    const int ktg = half * 16 + kt;
    if (kt < 15) {
      stage(cur ^ 1, ktg + 1);
      asm volatile("s_waitcnt vmcnt(4)" ::: "memory");  // own prev loads done
    } else {
      asm volatile("s_waitcnt vmcnt(0)" ::: "memory");
    }
    __builtin_amdgcn_sched_barrier(0);
    __builtin_amdgcn_s_barrier();  // all waves' tile-cur data in LDS
    const char* kb = myK + cur * 8192;
    const char* vb = myV + cur * 8192;
    const float* biasT = biasLDS + ktg * 64;
    do_subtile(kb, vb, biasT, 0, 0);
    do_subtile(kb, vb, biasT + 32, 4096, 2);
    __builtin_amdgcn_sched_barrier(0);
    __builtin_amdgcn_s_barrier();  // reads done before next overwrite
  }

  // ---- denominator: lanes l and l+32 hold complementary key subsets of q=l31 ----
  float rs = (rsp0 + rsp1) + (rsp2 + rsp3);
  rs += __shfl_xor(rs, 32);

  // ---- partner merge in [reg][lane] layout (bank = lane%32 -> conflict-free) ----
  float* oSh2 = (float*)ldsK;  // [4 wl][32 reg][64 lane] f32 = 32 KB
  u16* trb = (u16*)ldsV;       // [128 q][64 col] u16 = 16 KB
  if (half == 1) {
#pragma unroll
    for (int reg = 0; reg < 16; ++reg) {
      oSh2[(wl * 32 + reg) * 64 + lane] = o0[reg];
      oSh2[(wl * 32 + 16 + reg) * 64 + lane] = o1[reg];
    }
    if (h5 == 0) lShA[wl * 32 + l31] = rs;
  }
  __syncthreads();
  if (half == 0) {
    const float ltot = rs + lShA[wl * 32 + l31];  // l for q=l31 (all lanes)
    const float linv = 1.0f / ltot;
#pragma unroll
    for (int reg = 0; reg < 16; ++reg) {
      const int q = (reg & 3) + 8 * (reg >> 2) + 4 * h5;
      const float inv = __shfl(linv, q);
      const float v0 = (o0[reg] + oSh2[(wl * 32 + reg) * 64 + lane]) * inv;
      const float v1 = (o1[reg] + oSh2[(wl * 32 + 16 + reg) * 64 + lane]) * inv;
      trb[(wl * 32 + q) * 64 + l31] = f2bf(v0);
      trb[(wl * 32 + q) * 64 + 32 + l31] = f2bf(v1);
    }
  }
  __syncthreads();
  // ---- coalesced store: 128 rows x 64 cols bf16 ----
  const int h = bh & 7;
#pragma unroll
  for (int i = 0; i < 2; ++i) {
    const int ii = tid + i * 512;
    const int row = ii >> 3;
    const int c8 = (ii & 7) * 8;
    const u16x8 vv = *(const u16x8*)(trb + row * 64 + c8);
    const int grow = b * 2048 + qt * 128 + row;
    *(u16x8*)(attn + (size_t)grow * 512 + h * 64 + c8) = vv;
  }
}

// ---------------- output projection -> f32: 64x128 tiles, simple 2-phase ----------------
__global__ __launch_bounds__(256, 3) void gemm_out(const u16* __restrict__ attn,
                                                   const u16* __restrict__ woT,
                                                   const float* __restrict__ bo,
                                                   float* __restrict__ out) {
  __shared__ __align__(16) char lds[49152];  // 2 bufs x (A 8K + B 16K)
  const int hw = blockIdx.x;
  const int lg = (hw & 7) * 64 + (hw >> 3);
  const int m0 = (lg >> 2) * 64, n0 = (lg & 3) * 128;

  const int tid = threadIdx.x;
  const int lane = tid & 63;
  const int wave = tid >> 6;
  const int wm = wave >> 1, wn = wave & 1;
  const int srow = tid >> 3;
  const int sc16 = tid & 7;

  f32x4 acc[2][4] = {};

  auto stage = [&](int buf, int kt) {
    const int k0 = kt * 64;
    char* base = lds + buf * 24576;
#pragma unroll
    for (int c = 0; c < 2; ++c) {
      const int row = c * 32 + srow;
      const int xc = (sc16 ^ (row & 7)) << 3;
      gload16(attn + (size_t)(m0 + row) * 512 + k0 + xc,
              base + c * 4096 + (wave << 10));
    }
#pragma unroll
    for (int c = 0; c < 4; ++c) {
      const int row = c * 32 + srow;
      const int xc = (sc16 ^ (row & 7)) << 3;
      gload16(woT + (size_t)(n0 + row) * 512 + k0 + xc,
              base + 8192 + c * 4096 + (wave << 10));
    }
  };

  auto compute = [&](int buf) {
    const char* bA = lds + buf * 24576;
    const char* bB = bA + 8192;
#pragma unroll
    for (int kk = 0; kk < 2; ++kk) {
      const int c16 = kk * 4 + (lane >> 4);
      bf16x8 av[2], bv[4];
#pragma unroll
      for (int i = 0; i < 2; ++i) {
        const int row = wm * 32 + i * 16 + (lane & 15);
        av[i] = *(const bf16x8*)(bA + row * 128 + ((c16 ^ (row & 7)) << 4));
      }
#pragma unroll
      for (int j = 0; j < 4; ++j) {
        const int row = wn * 64 + j * 16 + (lane & 15);
        bv[j] = *(const bf16x8*)(bB + row * 128 + ((c16 ^ (row & 7)) << 4));
      }
#pragma unroll
      for (int i = 0; i < 2; ++i)
#pragma unroll
        for (int j = 0; j < 4; ++j)
          acc[i][j] = __builtin_amdgcn_mfma_f32_16x16x32_bf16(av[i], bv[j],
                                                              acc[i][j], 0, 0, 0);
    }
  };

  stage(0, 0);
  __syncthreads();
#pragma unroll
  for (int kt = 0; kt < 8; ++kt) {
    const int cur = kt & 1;
    if (kt < 7) stage(cur ^ 1, kt + 1);
    compute(cur);
    __syncthreads();
  }

#pragma unroll
  for (int j = 0; j < 4; ++j) {
    const int n = n0 + wn * 64 + j * 16 + (lane & 15);
    const float bn = bo[n];
#pragma unroll
    for (int i = 0; i < 2; ++i) {
      const int rbase = m0 + wm * 32 + i * 16 + ((lane >> 4) << 2);
#pragma unroll
      for (int r = 0; r < 4; ++r)
        out[(size_t)(rbase + r) * 512 + n] = acc[i][j][r] + bn;
    }
  }
}

extern "C" void kernel_launch(void* const* d_in, const int* in_sizes, int n_in,
                              void* d_out, int out_size, void* d_ws,
                              size_t ws_size, hipStream_t stream) {
  (void)in_sizes; (void)n_in; (void)out_size; (void)ws_size;
  const float* q = (const float*)d_in[0];
  const float* k = (const float*)d_in[1];
  const float* v = (const float*)d_in[2];
  const int* mask = (const int*)d_in[3];
  const float* wq = (const float*)d_in[4];
  const float* bq = (const float*)d_in[5];
  const float* wk = (const float*)d_in[6];
  const float* bk = (const float*)d_in[7];
  const float* wv = (const float*)d_in[8];
  const float* bv = (const float*)d_in[9];
  const float* wo = (const float*)d_in[10];
  const float* bo = (const float*)d_in[11];

  u16* xq = (u16*)d_ws;           // [8192][512] bf16 (3 inputs back-to-back)
  u16* xk = xq + 4194304;
  u16* xv = xk + 4194304;
  u16* wT = xv + 4194304;         // 4 x [512][512] bf16 transposed
  u16* qws = wT + 1048576;        // [32 bh][2048][64] bf16, pre-scaled
  u16* kws = qws + 4194304;       // [32 bh][2048][64] bf16
  u16* vTw = kws + 4194304;       // [32 bh][64][2048] bf16 (transposed)
  u16* attnb = xq;                // alias: xq dead after gemm_qkv
  float* out = (float*)d_out;

  conv_in<<<dim3(2048, 1, 3), 256, 0, stream>>>(q, k, v, xq);
  conv_w<<<dim3(8, 8, 4), 256, 0, stream>>>(wq, wk, wv, wo, wT);
  gemm_qkv<<<192, 512, 0, stream>>>(xq, xk, xv, wT, bq, bk, bv, qws, kws, vTw);
  attn_fwd<<<dim3(32, 16), 512, 0, stream>>>(qws, kws, vTw, mask, attnb);
  gemm_out<<<512, 256, 0, stream>>>(attnb, wT + 786432, bo, out);
}

// Round 13
// 100.670 us; speedup vs baseline: 1.7301x; 1.1305x over previous
//
#include <hip/hip_runtime.h>
#include <stdint.h>

// B=4, S=2048, D=512, H=8, DH=64
#define QSCALE (0.125f * 1.44269504088896340736f)  // 1/sqrt(DH) * log2(e), folded into Q
#define MASKNEG (-1.442695e9f)                      // -1e9 * log2(e)

typedef unsigned short u16;
typedef unsigned int u32;
typedef __bf16 bf16x8 __attribute__((ext_vector_type(8)));
typedef float f32x4 __attribute__((ext_vector_type(4)));
typedef float f32x16 __attribute__((ext_vector_type(16)));
typedef u16 u16x8 __attribute__((ext_vector_type(8)));
typedef u32 u32x4 __attribute__((ext_vector_type(4)));

__device__ __forceinline__ u16 f2bf(float f) {
  u32 u = __float_as_uint(f);
  u += 0x7fffu + ((u >> 16) & 1u);  // RNE
  return (u16)(u >> 16);
}

__device__ __forceinline__ u32 cvtpk(float lo, float hi) {
  u32 d;
  asm("v_cvt_pk_bf16_f32 %0, %1, %2" : "=v"(d) : "v"(lo), "v"(hi));
  return d;
}

// swap: high 32 lanes of a <-> low 32 lanes of b
__device__ __forceinline__ void plswap(u32& a, u32& b) {
  asm("v_permlane32_swap_b32 %0, %1" : "+v"(a), "+v"(b));
}

__device__ __forceinline__ void gload16(const void* src, void* ldsbase) {
  __builtin_amdgcn_global_load_lds(
      (const __attribute__((address_space(1))) u32*)src,
      (__attribute__((address_space(3))) u32*)ldsbase, 16, 0, 0);
}

// ------------- weight convert+transpose: f32 W[k][n] -> bf16 Wt[n][k] -------------
__global__ __launch_bounds__(256) void conv_w(const float* __restrict__ wq,
                                              const float* __restrict__ wk,
                                              const float* __restrict__ wv,
                                              const float* __restrict__ wo,
                                              u16* __restrict__ wT) {
  const float* src = (blockIdx.z == 0) ? wq : (blockIdx.z == 1) ? wk
                    : (blockIdx.z == 2) ? wv : wo;
  u16* dst = wT + (size_t)blockIdx.z * 262144;
  __shared__ float t[64][65];
  const int n0 = blockIdx.x * 64, k0 = blockIdx.y * 64;
  const int lr = threadIdx.x >> 6, lc = threadIdx.x & 63;
#pragma unroll
  for (int it = 0; it < 16; ++it) {
    const int row = it * 4 + lr;  // k offset
    t[row][lc] = src[(size_t)(k0 + row) * 512 + n0 + lc];
  }
  __syncthreads();
#pragma unroll
  for (int it = 0; it < 16; ++it) {
    const int row = it * 4 + lr;  // n offset
    dst[(size_t)(n0 + row) * 512 + k0 + lc] = f2bf(t[lc][row]);
  }
}

// ---------------- QKV projection: A staged as f32 via gload_lds, cvt in frag path ----------------
// No conv_in pass.  BK=32: A buf 16KB f32 + B buf 8KB bf16, double-buffered =
// 48KB -> 3 blocks/CU.  1D grid 768, XCD-bijective swizzle.
__global__ __launch_bounds__(256, 3) void gemm_qkv(
    const float* __restrict__ xqf, const float* __restrict__ xkf,
    const float* __restrict__ xvf, const u16* __restrict__ wT,
    const float* __restrict__ bq, const float* __restrict__ bk,
    const float* __restrict__ bv, u16* __restrict__ qws, u16* __restrict__ kws,
    u16* __restrict__ vTw) {
  __shared__ __align__(16) char lds[49152];
  const int hw = blockIdx.x;
  const int lg = (hw & 7) * 96 + (hw >> 3);
  const int z = lg >> 8;
  const int rem = lg & 255;
  const int m0 = (rem >> 2) * 128, n0 = (rem & 3) * 128;
  const float* A = (z == 0) ? xqf : (z == 1) ? xkf : xvf;
  const u16* Bt = wT + (size_t)z * 262144;
  const float* bias = (z == 0) ? bq : (z == 1) ? bk : bv;

  const int tid = threadIdx.x;
  const int lane = tid & 63;
  const int wave = tid >> 6;
  const int wm = wave >> 1, wn = wave & 1;
  const int h4 = lane >> 4, l15 = lane & 15;

  f32x4 acc[4][4] = {};

  // buf b: A at b*24576 (128 rows x 128B f32), B at b*24576+16384 (128 rows x 64B bf16)
  auto stage = [&](int buf, int kt) {
    const int k0 = kt * 32;
    char* baseA = lds + buf * 24576;
    char* baseB = baseA + 16384;
    {
      const int sxA = tid & 7;
#pragma unroll
      for (int c = 0; c < 4; ++c) {
        const int row = c * 32 + (tid >> 3);
        const int sx = sxA ^ (row & 7);
        gload16(A + (size_t)(m0 + row) * 512 + k0 + sx * 4,
                baseA + row * 128 + (sx << 4));
      }
    }
    {
      const int sxB = tid & 3;
#pragma unroll
      for (int c = 0; c < 2; ++c) {
        const int row = c * 64 + (tid >> 2);
        const int sx = sxB ^ (row & 3);
        gload16(Bt + (size_t)(n0 + row) * 512 + k0 + sx * 8,
                baseB + row * 64 + (sx << 4));
      }
    }
  };

  auto compute = [&](int buf) {
    const char* bA = lds + buf * 24576;
    const char* bB = bA + 16384;
    bf16x8 av[4], bv[4];
#pragma unroll
    for (int i = 0; i < 4; ++i) {
      const int row = wm * 64 + i * 16 + l15;
      const f32x4 lo =
          *(const f32x4*)(bA + row * 128 + (((h4 * 2) ^ (row & 7)) << 4));
      const f32x4 hi =
          *(const f32x4*)(bA + row * 128 + (((h4 * 2 + 1) ^ (row & 7)) << 4));
      u32x4 w;
      w[0] = cvtpk(lo[0], lo[1]);
      w[1] = cvtpk(lo[2], lo[3]);
      w[2] = cvtpk(hi[0], hi[1]);
      w[3] = cvtpk(hi[2], hi[3]);
      av[i] = __builtin_bit_cast(bf16x8, w);
    }
#pragma unroll
    for (int j = 0; j < 4; ++j) {
      const int row = wn * 64 + j * 16 + l15;
      bv[j] = *(const bf16x8*)(bB + row * 64 + ((h4 ^ (row & 3)) << 4));
    }
#pragma unroll
    for (int i = 0; i < 4; ++i)
#pragma unroll
      for (int j = 0; j < 4; ++j)
        acc[i][j] = __builtin_amdgcn_mfma_f32_16x16x32_bf16(av[i], bv[j],
                                                            acc[i][j], 0, 0, 0);
  };

  stage(0, 0);
  __syncthreads();
#pragma unroll
  for (int kt = 0; kt < 16; ++kt) {
    const int cur = kt & 1;
    if (kt < 15) stage(cur ^ 1, kt + 1);
    compute(cur);
    __syncthreads();
  }

  // epilogue
#pragma unroll
  for (int j = 0; j < 4; ++j) {
    const int n = n0 + wn * 64 + j * 16 + l15;
    const float bn = bias[n];
    const int h = n >> 6, dh = n & 63;
#pragma unroll
    for (int i = 0; i < 4; ++i) {
#pragma unroll
      for (int r = 0; r < 4; ++r) {
        const int rg = m0 + wm * 64 + i * 16 + h4 * 4 + r;
        const int b = rg >> 11, s = rg & 2047;
        const int bh = b * 8 + h;
        const float val = acc[i][j][r] + bn;
        if (z == 0) {
          qws[((size_t)bh * 2048 + s) * 64 + dh] = f2bf(val * QSCALE);
        } else if (z == 1) {
          kws[((size_t)bh * 2048 + s) * 64 + dh] = f2bf(val);
        } else {
          vTw[((size_t)bh * 64 + dh) * 2048 + s] = f2bf(val);
        }
      }
    }
  }
}

// ---------------- flash attention: 32x32 MFMA, in-register P, counted vmcnt ----------------
// grid (32 bh, 16 qt); 512 thr = 8 waves; waves 0-3 keys [0,1024), 4-7 [1024,2048).
__global__ __launch_bounds__(512, 4) void attn_fwd(
    const u16* __restrict__ qws, const u16* __restrict__ kws,
    const u16* __restrict__ vTw, const int* __restrict__ mask,
    u16* __restrict__ attn) {
  __shared__ __align__(16) char ldsK[32768];   // [2 halves][2 bufs][64 keys][128B]
  __shared__ __align__(16) char ldsV[32768];   // [2 halves][2 bufs][64 dh][128B]
  __shared__ __align__(16) float biasLDS[2048];
  __shared__ float lShA[128];

  const int bh = blockIdx.x;
  const int qt = blockIdx.y;
  const int b = bh >> 3;
  const int tid = threadIdx.x;
  const int lane = tid & 63, wave = tid >> 6;
  const int half = wave >> 2, wl = wave & 3;
  const int l31 = lane & 31, h5 = lane >> 5;

  // mask -> additive bias (exp2 domain), once per block
  {
    const int4 m4 = *(const int4*)(mask + b * 2048 + tid * 4);
    float4 bv;
    bv.x = m4.x ? MASKNEG : 0.0f;
    bv.y = m4.y ? MASKNEG : 0.0f;
    bv.z = m4.z ? MASKNEG : 0.0f;
    bv.w = m4.w ? MASKNEG : 0.0f;
    *(float4*)(biasLDS + tid * 4) = bv;
  }
  asm volatile("s_waitcnt lgkmcnt(0)" ::: "memory");

  // Q fragments (already scaled): B-operand, col=q=l31, k = c*16 + h5*8 + j
  const u16* qrow_p = qws + ((size_t)bh * 2048 + qt * 128 + wl * 32 + l31) * 64;
  bf16x8 qb[4];
#pragma unroll
  for (int c = 0; c < 4; ++c)
    qb[c] = *(const bf16x8*)(qrow_p + c * 16 + h5 * 8);

  // hoisted addressing
  const int rowb = l31 * 128;
  int kxs[4];
#pragma unroll
  for (int c = 0; c < 4; ++c) kxs[c] = ((2 * c + h5) ^ (l31 & 7)) << 4;

  char* myK = ldsK + half * 16384;
  char* myV = ldsV + half * 16384;
  const int srow = wl * 8 + (lane >> 3);
  const int sc16 = lane & 7;

  auto stage = [&](int buf, int ktg) {
#pragma unroll
    for (int c = 0; c < 2; ++c) {
      const int row = c * 32 + srow;
      const int xc = (sc16 ^ (row & 7)) << 3;
      gload16(kws + ((size_t)bh * 2048 + ktg * 64 + row) * 64 + xc,
              myK + buf * 8192 + c * 4096 + (wl << 10));
      gload16(vTw + ((size_t)bh * 64 + row) * 2048 + ktg * 64 + xc,
              myV + buf * 8192 + c * 4096 + (wl << 10));
    }
  };

  f32x16 o0 = {}, o1 = {};
  float rsp0 = 0.f, rsp1 = 0.f, rsp2 = 0.f, rsp3 = 0.f;

  auto do_subtile = [&](const char* kb, const char* vb, const float* biasT,
                        int stByte, int c0) {
    // acc init = mask bias (broadcast b128 reads)
    f32x16 sv;
#pragma unroll
    for (int g = 0; g < 4; ++g) {
      const f32x4 bq4 = *(const f32x4*)(biasT + g * 8 + h5 * 4);
      sv[g * 4 + 0] = bq4[0];
      sv[g * 4 + 1] = bq4[1];
      sv[g * 4 + 2] = bq4[2];
      sv[g * 4 + 3] = bq4[3];
    }
    // S^T += K Q^T
    __builtin_amdgcn_s_setprio(1);
#pragma unroll
    for (int c = 0; c < 4; ++c) {
      const bf16x8 kf = *(const bf16x8*)(kb + stByte + rowb + kxs[c]);
      sv = __builtin_amdgcn_mfma_f32_32x32x16_bf16(kf, qb[c], sv, 0, 0, 0);
    }
    __builtin_amdgcn_s_setprio(0);
    // exp2 (masked keys -> exactly 0) + denom partials
    float p[16];
#pragma unroll
    for (int i = 0; i < 16; ++i) p[i] = __builtin_amdgcn_exp2f(sv[i]);
    rsp0 += p[0] + p[4] + p[8] + p[12];
    rsp1 += p[1] + p[5] + p[9] + p[13];
    rsp2 += p[2] + p[6] + p[10] + p[14];
    rsp3 += p[3] + p[7] + p[11] + p[15];
    // pack P -> PV A-frags via cvt_pk + permlane32_swap (no LDS)
    u32 paw[2][4];
#pragma unroll
    for (int lc = 0; lc < 2; ++lc) {
      u32 a1 = cvtpk(p[lc * 8 + 0], p[lc * 8 + 1]);
      u32 b1 = cvtpk(p[lc * 8 + 4], p[lc * 8 + 5]);
      u32 a2 = cvtpk(p[lc * 8 + 2], p[lc * 8 + 3]);
      u32 b2 = cvtpk(p[lc * 8 + 6], p[lc * 8 + 7]);
      plswap(a1, b1);
      plswap(a2, b2);
      paw[lc][0] = a1; paw[lc][1] = a2; paw[lc][2] = b1; paw[lc][3] = b2;
    }
    // O += P V
    __builtin_amdgcn_s_setprio(1);
#pragma unroll
    for (int lc = 0; lc < 2; ++lc) {
      u32x4 w = {paw[lc][0], paw[lc][1], paw[lc][2], paw[lc][3]};
      const bf16x8 pa = __builtin_bit_cast(bf16x8, w);
      const bf16x8 vf0 = *(const bf16x8*)(vb + rowb + kxs[c0 + lc]);
      o0 = __builtin_amdgcn_mfma_f32_32x32x16_bf16(pa, vf0, o0, 0, 0, 0);
      const bf16x8 vf1 = *(const bf16x8*)(vb + 4096 + rowb + kxs[c0 + lc]);
      o1 = __builtin_amdgcn_mfma_f32_32x32x16_bf16(pa, vf1, o1, 0, 0, 0);
    }
    __builtin_amdgcn_s_setprio(0);
  };

  stage(0, half * 16);

  for (int kt = 0; kt < 16; ++kt) {
    const int cur = kt & 1;
    const int ktg = half * 16 + kt;
    if (kt < 15) {
      stage(cur ^ 1, ktg + 1);
      asm volatile("s_waitcnt vmcnt(4)" ::: "memory");  // own prev loads done
    } else {
      asm volatile("s_waitcnt vmcnt(0)" ::: "memory");
    }
    __builtin_amdgcn_sched_barrier(0);
    __builtin_amdgcn_s_barrier();  // all waves' tile-cur data in LDS
    const char* kb = myK + cur * 8192;
    const char* vb = myV + cur * 8192;
    const float* biasT = biasLDS + ktg * 64;
    do_subtile(kb, vb, biasT, 0, 0);
    do_subtile(kb, vb, biasT + 32, 4096, 2);
    __builtin_amdgcn_sched_barrier(0);
    __builtin_amdgcn_s_barrier();  // reads done before next overwrite
  }

  // ---- denominator: lanes l and l+32 hold complementary key subsets of q=l31 ----
  float rs = (rsp0 + rsp1) + (rsp2 + rsp3);
  rs += __shfl_xor(rs, 32);

  // ---- partner merge in [reg][lane] layout (bank = lane%32 -> conflict-free) ----
  float* oSh2 = (float*)ldsK;  // [4 wl][32 reg][64 lane] f32 = 32 KB
  u16* trb = (u16*)ldsV;       // [128 q][64 col] u16 = 16 KB
  if (half == 1) {
#pragma unroll
    for (int reg = 0; reg < 16; ++reg) {
      oSh2[(wl * 32 + reg) * 64 + lane] = o0[reg];
      oSh2[(wl * 32 + 16 + reg) * 64 + lane] = o1[reg];
    }
    if (h5 == 0) lShA[wl * 32 + l31] = rs;
  }
  __syncthreads();
  if (half == 0) {
    const float ltot = rs + lShA[wl * 32 + l31];  // l for q=l31 (all lanes)
    const float linv = 1.0f / ltot;
#pragma unroll
    for (int reg = 0; reg < 16; ++reg) {
      const int q = (reg & 3) + 8 * (reg >> 2) + 4 * h5;
      const float inv = __shfl(linv, q);
      const float v0 = (o0[reg] + oSh2[(wl * 32 + reg) * 64 + lane]) * inv;
      const float v1 = (o1[reg] + oSh2[(wl * 32 + 16 + reg) * 64 + lane]) * inv;
      trb[(wl * 32 + q) * 64 + l31] = f2bf(v0);
      trb[(wl * 32 + q) * 64 + 32 + l31] = f2bf(v1);
    }
  }
  __syncthreads();
  // ---- coalesced store: 128 rows x 64 cols bf16 ----
  const int h = bh & 7;
#pragma unroll
  for (int i = 0; i < 2; ++i) {
    const int ii = tid + i * 512;
    const int row = ii >> 3;
    const int c8 = (ii & 7) * 8;
    const u16x8 vv = *(const u16x8*)(trb + row * 64 + c8);
    const int grow = b * 2048 + qt * 128 + row;
    *(u16x8*)(attn + (size_t)grow * 512 + h * 64 + c8) = vv;
  }
}

// ---------------- output projection -> f32: 64x128 tiles, simple 2-phase ----------------
__global__ __launch_bounds__(256, 3) void gemm_out(const u16* __restrict__ attn,
                                                   const u16* __restrict__ woT,
                                                   const float* __restrict__ bo,
                                                   float* __restrict__ out) {
  __shared__ __align__(16) char lds[49152];  // 2 bufs x (A 8K + B 16K)
  const int hw = blockIdx.x;
  const int lg = (hw & 7) * 64 + (hw >> 3);
  const int m0 = (lg >> 2) * 64, n0 = (lg & 3) * 128;

  const int tid = threadIdx.x;
  const int lane = tid & 63;
  const int wave = tid >> 6;
  const int wm = wave >> 1, wn = wave & 1;
  const int srow = tid >> 3;
  const int sc16 = tid & 7;

  f32x4 acc[2][4] = {};

  auto stage = [&](int buf, int kt) {
    const int k0 = kt * 64;
    char* base = lds + buf * 24576;
#pragma unroll
    for (int c = 0; c < 2; ++c) {
      const int row = c * 32 + srow;
      const int xc = (sc16 ^ (row & 7)) << 3;
      gload16(attn + (size_t)(m0 + row) * 512 + k0 + xc,
              base + c * 4096 + (wave << 10));
    }
#pragma unroll
    for (int c = 0; c < 4; ++c) {
      const int row = c * 32 + srow;
      const int xc = (sc16 ^ (row & 7)) << 3;
      gload16(woT + (size_t)(n0 + row) * 512 + k0 + xc,
              base + 8192 + c * 4096 + (wave << 10));
    }
  };

  auto compute = [&](int buf) {
    const char* bA = lds + buf * 24576;
    const char* bB = bA + 8192;
#pragma unroll
    for (int kk = 0; kk < 2; ++kk) {
      const int c16 = kk * 4 + (lane >> 4);
      bf16x8 av[2], bv[4];
#pragma unroll
      for (int i = 0; i < 2; ++i) {
        const int row = wm * 32 + i * 16 + (lane & 15);
        av[i] = *(const bf16x8*)(bA + row * 128 + ((c16 ^ (row & 7)) << 4));
      }
#pragma unroll
      for (int j = 0; j < 4; ++j) {
        const int row = wn * 64 + j * 16 + (lane & 15);
        bv[j] = *(const bf16x8*)(bB + row * 128 + ((c16 ^ (row & 7)) << 4));
      }
#pragma unroll
      for (int i = 0; i < 2; ++i)
#pragma unroll
        for (int j = 0; j < 4; ++j)
          acc[i][j] = __builtin_amdgcn_mfma_f32_16x16x32_bf16(av[i], bv[j],
                                                              acc[i][j], 0, 0, 0);
    }
  };

  stage(0, 0);
  __syncthreads();
#pragma unroll
  for (int kt = 0; kt < 8; ++kt) {
    const int cur = kt & 1;
    if (kt < 7) stage(cur ^ 1, kt + 1);
    compute(cur);
    __syncthreads();
  }

#pragma unroll
  for (int j = 0; j < 4; ++j) {
    const int n = n0 + wn * 64 + j * 16 + (lane & 15);
    const float bn = bo[n];
#pragma unroll
    for (int i = 0; i < 2; ++i) {
      const int rbase = m0 + wm * 32 + i * 16 + ((lane >> 4) << 2);
#pragma unroll
      for (int r = 0; r < 4; ++r)
        out[(size_t)(rbase + r) * 512 + n] = acc[i][j][r] + bn;
    }
  }
}

extern "C" void kernel_launch(void* const* d_in, const int* in_sizes, int n_in,
                              void* d_out, int out_size, void* d_ws,
                              size_t ws_size, hipStream_t stream) {
  (void)in_sizes; (void)n_in; (void)out_size; (void)ws_size;
  const float* q = (const float*)d_in[0];
  const float* k = (const float*)d_in[1];
  const float* v = (const float*)d_in[2];
  const int* mask = (const int*)d_in[3];
  const float* wq = (const float*)d_in[4];
  const float* bq = (const float*)d_in[5];
  const float* wk = (const float*)d_in[6];
  const float* bk = (const float*)d_in[7];
  const float* wv = (const float*)d_in[8];
  const float* bv = (const float*)d_in[9];
  const float* wo = (const float*)d_in[10];
  const float* bo = (const float*)d_in[11];

  u16* attnb = (u16*)d_ws;        // [8192][512] bf16 attention output
  u16* wT = attnb + 4194304;      // 4 x [512][512] bf16 transposed
  u16* qws = wT + 1048576;        // [32 bh][2048][64] bf16, pre-scaled
  u16* kws = qws + 4194304;       // [32 bh][2048][64] bf16
  u16* vTw = kws + 4194304;       // [32 bh][64][2048] bf16 (transposed)
  float* out = (float*)d_out;

  conv_w<<<dim3(8, 8, 4), 256, 0, stream>>>(wq, wk, wv, wo, wT);
  gemm_qkv<<<768, 256, 0, stream>>>(q, k, v, wT, bq, bk, bv, qws, kws, vTw);
  attn_fwd<<<dim3(32, 16), 512, 0, stream>>>(qws, kws, vTw, mask, attnb);
  gemm_out<<<512, 256, 0, stream>>>(attnb, wT + 786432, bo, out);
}

// Round 14
// 100.458 us; speedup vs baseline: 1.7337x; 1.0021x over previous
//
#include <hip/hip_runtime.h>
#include <stdint.h>

// B=4, S=2048, D=512, H=8, DH=64
#define QSCALE (0.125f * 1.44269504088896340736f)  // 1/sqrt(DH) * log2(e), folded into Q
#define MASKNEG (-1.442695e9f)                      // -1e9 * log2(e)

typedef unsigned short u16;
typedef unsigned int u32;
typedef __bf16 bf16x8 __attribute__((ext_vector_type(8)));
typedef float f32x4 __attribute__((ext_vector_type(4)));
typedef float f32x16 __attribute__((ext_vector_type(16)));
typedef u16 u16x8 __attribute__((ext_vector_type(8)));
typedef u32 u32x4 __attribute__((ext_vector_type(4)));

__device__ __forceinline__ u16 f2bf(float f) {
  u32 u = __float_as_uint(f);
  u += 0x7fffu + ((u >> 16) & 1u);  // RNE
  return (u16)(u >> 16);
}

__device__ __forceinline__ u32 cvtpk(float lo, float hi) {
  u32 d;
  asm("v_cvt_pk_bf16_f32 %0, %1, %2" : "=v"(d) : "v"(lo), "v"(hi));
  return d;
}

// swap: high 32 lanes of a <-> low 32 lanes of b
__device__ __forceinline__ void plswap(u32& a, u32& b) {
  asm("v_permlane32_swap_b32 %0, %1" : "+v"(a), "+v"(b));
}

__device__ __forceinline__ void gload16(const void* src, void* ldsbase) {
  __builtin_amdgcn_global_load_lds(
      (const __attribute__((address_space(1))) u32*)src,
      (__attribute__((address_space(3))) u32*)ldsbase, 16, 0, 0);
}

// ------------- weight convert+transpose: f32 W[k][n] -> bf16 Wt[n][k] -------------
__global__ __launch_bounds__(256) void conv_w(const float* __restrict__ wq,
                                              const float* __restrict__ wk,
                                              const float* __restrict__ wv,
                                              const float* __restrict__ wo,
                                              u16* __restrict__ wT) {
  const float* src = (blockIdx.z == 0) ? wq : (blockIdx.z == 1) ? wk
                    : (blockIdx.z == 2) ? wv : wo;
  u16* dst = wT + (size_t)blockIdx.z * 262144;
  __shared__ float t[64][65];
  const int n0 = blockIdx.x * 64, k0 = blockIdx.y * 64;
  const int lr = threadIdx.x >> 6, lc = threadIdx.x & 63;
#pragma unroll
  for (int it = 0; it < 16; ++it) {
    const int row = it * 4 + lr;  // k offset
    t[row][lc] = src[(size_t)(k0 + row) * 512 + n0 + lc];
  }
  __syncthreads();
#pragma unroll
  for (int it = 0; it < 16; ++it) {
    const int row = it * 4 + lr;  // n offset
    dst[(size_t)(n0 + row) * 512 + k0 + lc] = f2bf(t[lc][row]);
  }
}

// ---------------- QKV projection: A staged as f32 via gload_lds, cvt in frag path ----------------
// No conv_in pass.  BK=32: A buf 16KB f32 + B buf 8KB bf16, double-buffered =
// 48KB -> 3 blocks/CU.  1D grid 768, XCD-bijective swizzle.
// B swizzle uses t(r) = (r ^ (r>>2)) & 3 so lanes sharing (l15&3) land on
// different slots -> bank conflicts 4-way -> 2-way (free).
__global__ __launch_bounds__(256, 3) void gemm_qkv(
    const float* __restrict__ xqf, const float* __restrict__ xkf,
    const float* __restrict__ xvf, const u16* __restrict__ wT,
    const float* __restrict__ bq, const float* __restrict__ bk,
    const float* __restrict__ bv, u16* __restrict__ qws, u16* __restrict__ kws,
    u16* __restrict__ vTw) {
  __shared__ __align__(16) char lds[49152];
  const int hw = blockIdx.x;
  const int lg = (hw & 7) * 96 + (hw >> 3);
  const int z = lg >> 8;
  const int rem = lg & 255;
  const int m0 = (rem >> 2) * 128, n0 = (rem & 3) * 128;
  const float* A = (z == 0) ? xqf : (z == 1) ? xkf : xvf;
  const u16* Bt = wT + (size_t)z * 262144;
  const float* bias = (z == 0) ? bq : (z == 1) ? bk : bv;

  const int tid = threadIdx.x;
  const int lane = tid & 63;
  const int wave = tid >> 6;
  const int wm = wave >> 1, wn = wave & 1;
  const int h4 = lane >> 4, l15 = lane & 15;

  f32x4 acc[4][4] = {};

  // buf b: A at b*24576 (128 rows x 128B f32), B at b*24576+16384 (128 rows x 64B bf16)
  auto stage = [&](int buf, int kt) {
    const int k0 = kt * 32;
    char* baseA = lds + buf * 24576;
    char* baseB = baseA + 16384;
    {
      const int sxA = tid & 7;
#pragma unroll
      for (int c = 0; c < 4; ++c) {
        const int row = c * 32 + (tid >> 3);
        const int sx = sxA ^ (row & 7);
        gload16(A + (size_t)(m0 + row) * 512 + k0 + sx * 4,
                baseA + row * 128 + (sx << 4));
      }
    }
    {
      const int sxB = tid & 3;
#pragma unroll
      for (int c = 0; c < 2; ++c) {
        const int row = c * 64 + (tid >> 2);
        const int sx = sxB ^ ((row ^ (row >> 2)) & 3);
        gload16(Bt + (size_t)(n0 + row) * 512 + k0 + sx * 8,
                baseB + row * 64 + (sx << 4));
      }
    }
  };

  auto compute = [&](int buf) {
    const char* bA = lds + buf * 24576;
    const char* bB = bA + 16384;
    bf16x8 av[4], bv[4];
#pragma unroll
    for (int i = 0; i < 4; ++i) {
      const int row = wm * 64 + i * 16 + l15;
      const f32x4 lo =
          *(const f32x4*)(bA + row * 128 + (((h4 * 2) ^ (row & 7)) << 4));
      const f32x4 hi =
          *(const f32x4*)(bA + row * 128 + (((h4 * 2 + 1) ^ (row & 7)) << 4));
      u32x4 w;
      w[0] = cvtpk(lo[0], lo[1]);
      w[1] = cvtpk(lo[2], lo[3]);
      w[2] = cvtpk(hi[0], hi[1]);
      w[3] = cvtpk(hi[2], hi[3]);
      av[i] = __builtin_bit_cast(bf16x8, w);
    }
#pragma unroll
    for (int j = 0; j < 4; ++j) {
      const int row = wn * 64 + j * 16 + l15;
      bv[j] = *(const bf16x8*)(bB + row * 64 +
                               ((h4 ^ ((row ^ (row >> 2)) & 3)) << 4));
    }
#pragma unroll
    for (int i = 0; i < 4; ++i)
#pragma unroll
      for (int j = 0; j < 4; ++j)
        acc[i][j] = __builtin_amdgcn_mfma_f32_16x16x32_bf16(av[i], bv[j],
                                                            acc[i][j], 0, 0, 0);
  };

  stage(0, 0);
  __syncthreads();
#pragma unroll
  for (int kt = 0; kt < 16; ++kt) {
    const int cur = kt & 1;
    if (kt < 15) stage(cur ^ 1, kt + 1);
    compute(cur);
    __syncthreads();
  }

  // epilogue
#pragma unroll
  for (int j = 0; j < 4; ++j) {
    const int n = n0 + wn * 64 + j * 16 + l15;
    const float bn = bias[n];
    const int h = n >> 6, dh = n & 63;
#pragma unroll
    for (int i = 0; i < 4; ++i) {
#pragma unroll
      for (int r = 0; r < 4; ++r) {
        const int rg = m0 + wm * 64 + i * 16 + h4 * 4 + r;
        const int b = rg >> 11, s = rg & 2047;
        const int bh = b * 8 + h;
        const float val = acc[i][j][r] + bn;
        if (z == 0) {
          qws[((size_t)bh * 2048 + s) * 64 + dh] = f2bf(val * QSCALE);
        } else if (z == 1) {
          kws[((size_t)bh * 2048 + s) * 64 + dh] = f2bf(val);
        } else {
          vTw[((size_t)bh * 64 + dh) * 2048 + s] = f2bf(val);
        }
      }
    }
  }
}

// ---------------- flash attention: 32x32 MFMA, in-register P, counted vmcnt ----------------
// grid (32 bh, 16 qt); 512 thr = 8 waves; waves 0-3 keys [0,1024), 4-7 [1024,2048).
// K/V LDS rows are 128B (= 32 banks), so slot^(row&7) left lanes sharing
// (l31&7) on identical banks (4-way).  Swizzle now t(row)=(row^(row>>3))&7:
// rows +8/+16/+24 land on distinct slots -> conflict-free.  Subtile-2 reads
// (rows +32) flip bit2 of t -> byte offset ^64.
__global__ __launch_bounds__(512, 4) void attn_fwd(
    const u16* __restrict__ qws, const u16* __restrict__ kws,
    const u16* __restrict__ vTw, const int* __restrict__ mask,
    u16* __restrict__ attn) {
  __shared__ __align__(16) char ldsK[32768];   // [2 halves][2 bufs][64 keys][128B]
  __shared__ __align__(16) char ldsV[32768];   // [2 halves][2 bufs][64 dh][128B]
  __shared__ __align__(16) float biasLDS[2048];
  __shared__ float lShA[128];

  const int bh = blockIdx.x;
  const int qt = blockIdx.y;
  const int b = bh >> 3;
  const int tid = threadIdx.x;
  const int lane = tid & 63, wave = tid >> 6;
  const int half = wave >> 2, wl = wave & 3;
  const int l31 = lane & 31, h5 = lane >> 5;

  // mask -> additive bias (exp2 domain), once per block
  {
    const int4 m4 = *(const int4*)(mask + b * 2048 + tid * 4);
    float4 bv;
    bv.x = m4.x ? MASKNEG : 0.0f;
    bv.y = m4.y ? MASKNEG : 0.0f;
    bv.z = m4.z ? MASKNEG : 0.0f;
    bv.w = m4.w ? MASKNEG : 0.0f;
    *(float4*)(biasLDS + tid * 4) = bv;
  }
  asm volatile("s_waitcnt lgkmcnt(0)" ::: "memory");

  // Q fragments (already scaled): B-operand, col=q=l31, k = c*16 + h5*8 + j
  const u16* qrow_p = qws + ((size_t)bh * 2048 + qt * 128 + wl * 32 + l31) * 64;
  bf16x8 qb[4];
#pragma unroll
  for (int c = 0; c < 4; ++c)
    qb[c] = *(const bf16x8*)(qrow_p + c * 16 + h5 * 8);

  // hoisted addressing: t(l31) = (l31 ^ (l31>>3)) & 7 spreads rows over banks
  const int rowb = l31 * 128;
  const int tl = (l31 ^ (l31 >> 3)) & 7;
  int kxs[4];
#pragma unroll
  for (int c = 0; c < 4; ++c) kxs[c] = ((2 * c + h5) ^ tl) << 4;

  char* myK = ldsK + half * 16384;
  char* myV = ldsV + half * 16384;
  const int srow = wl * 8 + (lane >> 3);
  const int sc16 = lane & 7;

  auto stage = [&](int buf, int ktg) {
#pragma unroll
    for (int c = 0; c < 2; ++c) {
      const int row = c * 32 + srow;
      const int xc = (sc16 ^ ((row ^ (row >> 3)) & 7)) << 3;
      gload16(kws + ((size_t)bh * 2048 + ktg * 64 + row) * 64 + xc,
              myK + buf * 8192 + c * 4096 + (wl << 10));
      gload16(vTw + ((size_t)bh * 64 + row) * 2048 + ktg * 64 + xc,
              myV + buf * 8192 + c * 4096 + (wl << 10));
    }
  };

  f32x16 o0 = {}, o1 = {};
  float rsp0 = 0.f, rsp1 = 0.f, rsp2 = 0.f, rsp3 = 0.f;

  auto do_subtile = [&](const char* kb, const char* vb, const float* biasT,
                        int stByte, int c0) {
    const int xadj = stByte ? 64 : 0;  // rows+32: t ^= 4 -> byte ^= 64
    // acc init = mask bias (broadcast b128 reads)
    f32x16 sv;
#pragma unroll
    for (int g = 0; g < 4; ++g) {
      const f32x4 bq4 = *(const f32x4*)(biasT + g * 8 + h5 * 4);
      sv[g * 4 + 0] = bq4[0];
      sv[g * 4 + 1] = bq4[1];
      sv[g * 4 + 2] = bq4[2];
      sv[g * 4 + 3] = bq4[3];
    }
    // S^T += K Q^T
    __builtin_amdgcn_s_setprio(1);
#pragma unroll
    for (int c = 0; c < 4; ++c) {
      const bf16x8 kf = *(const bf16x8*)(kb + stByte + rowb + (kxs[c] ^ xadj));
      sv = __builtin_amdgcn_mfma_f32_32x32x16_bf16(kf, qb[c], sv, 0, 0, 0);
    }
    __builtin_amdgcn_s_setprio(0);
    // exp2 (masked keys -> exactly 0) + denom partials
    float p[16];
#pragma unroll
    for (int i = 0; i < 16; ++i) p[i] = __builtin_amdgcn_exp2f(sv[i]);
    rsp0 += p[0] + p[4] + p[8] + p[12];
    rsp1 += p[1] + p[5] + p[9] + p[13];
    rsp2 += p[2] + p[6] + p[10] + p[14];
    rsp3 += p[3] + p[7] + p[11] + p[15];
    // pack P -> PV A-frags via cvt_pk + permlane32_swap (no LDS)
    u32 paw[2][4];
#pragma unroll
    for (int lc = 0; lc < 2; ++lc) {
      u32 a1 = cvtpk(p[lc * 8 + 0], p[lc * 8 + 1]);
      u32 b1 = cvtpk(p[lc * 8 + 4], p[lc * 8 + 5]);
      u32 a2 = cvtpk(p[lc * 8 + 2], p[lc * 8 + 3]);
      u32 b2 = cvtpk(p[lc * 8 + 6], p[lc * 8 + 7]);
      plswap(a1, b1);
      plswap(a2, b2);
      paw[lc][0] = a1; paw[lc][1] = a2; paw[lc][2] = b1; paw[lc][3] = b2;
    }
    // O += P V
    __builtin_amdgcn_s_setprio(1);
#pragma unroll
    for (int lc = 0; lc < 2; ++lc) {
      u32x4 w = {paw[lc][0], paw[lc][1], paw[lc][2], paw[lc][3]};
      const bf16x8 pa = __builtin_bit_cast(bf16x8, w);
      const bf16x8 vf0 = *(const bf16x8*)(vb + rowb + kxs[c0 + lc]);
      o0 = __builtin_amdgcn_mfma_f32_32x32x16_bf16(pa, vf0, o0, 0, 0, 0);
      const bf16x8 vf1 =
          *(const bf16x8*)(vb + 4096 + rowb + (kxs[c0 + lc] ^ 64));
      o1 = __builtin_amdgcn_mfma_f32_32x32x16_bf16(pa, vf1, o1, 0, 0, 0);
    }
    __builtin_amdgcn_s_setprio(0);
  };

  stage(0, half * 16);

  for (int kt = 0; kt < 16; ++kt) {
    const int cur = kt & 1;
    const int ktg = half * 16 + kt;
    if (kt < 15) {
      stage(cur ^ 1, ktg + 1);
      asm volatile("s_waitcnt vmcnt(4)" ::: "memory");  // own prev loads done
    } else {
      asm volatile("s_waitcnt vmcnt(0)" ::: "memory");
    }
    __builtin_amdgcn_sched_barrier(0);
    __builtin_amdgcn_s_barrier();  // all waves' tile-cur data in LDS
    const char* kb = myK + cur * 8192;
    const char* vb = myV + cur * 8192;
    const float* biasT = biasLDS + ktg * 64;
    do_subtile(kb, vb, biasT, 0, 0);
    do_subtile(kb, vb, biasT + 32, 4096, 2);
    __builtin_amdgcn_sched_barrier(0);
    __builtin_amdgcn_s_barrier();  // reads done before next overwrite
  }

  // ---- denominator: lanes l and l+32 hold complementary key subsets of q=l31 ----
  float rs = (rsp0 + rsp1) + (rsp2 + rsp3);
  rs += __shfl_xor(rs, 32);

  // ---- partner merge in [reg][lane] layout (bank = lane%32 -> conflict-free) ----
  float* oSh2 = (float*)ldsK;  // [4 wl][32 reg][64 lane] f32 = 32 KB
  u16* trb = (u16*)ldsV;       // [128 q][64 col] u16 = 16 KB
  if (half == 1) {
#pragma unroll
    for (int reg = 0; reg < 16; ++reg) {
      oSh2[(wl * 32 + reg) * 64 + lane] = o0[reg];
      oSh2[(wl * 32 + 16 + reg) * 64 + lane] = o1[reg];
    }
    if (h5 == 0) lShA[wl * 32 + l31] = rs;
  }
  __syncthreads();
  if (half == 0) {
    const float ltot = rs + lShA[wl * 32 + l31];  // l for q=l31 (all lanes)
    const float linv = 1.0f / ltot;
#pragma unroll
    for (int reg = 0; reg < 16; ++reg) {
      const int q = (reg & 3) + 8 * (reg >> 2) + 4 * h5;
      const float inv = __shfl(linv, q);
      const float v0 = (o0[reg] + oSh2[(wl * 32 + reg) * 64 + lane]) * inv;
      const float v1 = (o1[reg] + oSh2[(wl * 32 + 16 + reg) * 64 + lane]) * inv;
      trb[(wl * 32 + q) * 64 + l31] = f2bf(v0);
      trb[(wl * 32 + q) * 64 + 32 + l31] = f2bf(v1);
    }
  }
  __syncthreads();
  // ---- coalesced store: 128 rows x 64 cols bf16 ----
  const int h = bh & 7;
#pragma unroll
  for (int i = 0; i < 2; ++i) {
    const int ii = tid + i * 512;
    const int row = ii >> 3;
    const int c8 = (ii & 7) * 8;
    const u16x8 vv = *(const u16x8*)(trb + row * 64 + c8);
    const int grow = b * 2048 + qt * 128 + row;
    *(u16x8*)(attn + (size_t)grow * 512 + h * 64 + c8) = vv;
  }
}

// ---------------- output projection -> f32: 64x128 tiles, simple 2-phase ----------------
__global__ __launch_bounds__(256, 3) void gemm_out(const u16* __restrict__ attn,
                                                   const u16* __restrict__ woT,
                                                   const float* __restrict__ bo,
                                                   float* __restrict__ out) {
  __shared__ __align__(16) char lds[49152];  // 2 bufs x (A 8K + B 16K)
  const int hw = blockIdx.x;
  const int lg = (hw & 7) * 64 + (hw >> 3);
  const int m0 = (lg >> 2) * 64, n0 = (lg & 3) * 128;

  const int tid = threadIdx.x;
  const int lane = tid & 63;
  const int wave = tid >> 6;
  const int wm = wave >> 1, wn = wave & 1;
  const int srow = tid >> 3;
  const int sc16 = tid & 7;

  f32x4 acc[2][4] = {};

  auto stage = [&](int buf, int kt) {
    const int k0 = kt * 64;
    char* base = lds + buf * 24576;
#pragma unroll
    for (int c = 0; c < 2; ++c) {
      const int row = c * 32 + srow;
      const int xc = (sc16 ^ (row & 7)) << 3;
      gload16(attn + (size_t)(m0 + row) * 512 + k0 + xc,
              base + c * 4096 + (wave << 10));
    }
#pragma unroll
    for (int c = 0; c < 4; ++c) {
      const int row = c * 32 + srow;
      const int xc = (sc16 ^ (row & 7)) << 3;
      gload16(woT + (size_t)(n0 + row) * 512 + k0 + xc,
              base + 8192 + c * 4096 + (wave << 10));
    }
  };

  auto compute = [&](int buf) {
    const char* bA = lds + buf * 24576;
    const char* bB = bA + 8192;
#pragma unroll
    for (int kk = 0; kk < 2; ++kk) {
      const int c16 = kk * 4 + (lane >> 4);
      bf16x8 av[2], bv[4];
#pragma unroll
      for (int i = 0; i < 2; ++i) {
        const int row = wm * 32 + i * 16 + (lane & 15);
        av[i] = *(const bf16x8*)(bA + row * 128 + ((c16 ^ (row & 7)) << 4));
      }
#pragma unroll
      for (int j = 0; j < 4; ++j) {
        const int row = wn * 64 + j * 16 + (lane & 15);
        bv[j] = *(const bf16x8*)(bB + row * 128 + ((c16 ^ (row & 7)) << 4));
      }
#pragma unroll
      for (int i = 0; i < 2; ++i)
#pragma unroll
        for (int j = 0; j < 4; ++j)
          acc[i][j] = __builtin_amdgcn_mfma_f32_16x16x32_bf16(av[i], bv[j],
                                                              acc[i][j], 0, 0, 0);
    }
  };

  stage(0, 0);
  __syncthreads();
#pragma unroll
  for (int kt = 0; kt < 8; ++kt) {
    const int cur = kt & 1;
    if (kt < 7) stage(cur ^ 1, kt + 1);
    compute(cur);
    __syncthreads();
  }

#pragma unroll
  for (int j = 0; j < 4; ++j) {
    const int n = n0 + wn * 64 + j * 16 + (lane & 15);
    const float bn = bo[n];
#pragma unroll
    for (int i = 0; i < 2; ++i) {
      const int rbase = m0 + wm * 32 + i * 16 + ((lane >> 4) << 2);
#pragma unroll
      for (int r = 0; r < 4; ++r)
        out[(size_t)(rbase + r) * 512 + n] = acc[i][j][r] + bn;
    }
  }
}

extern "C" void kernel_launch(void* const* d_in, const int* in_sizes, int n_in,
                              void* d_out, int out_size, void* d_ws,
                              size_t ws_size, hipStream_t stream) {
  (void)in_sizes; (void)n_in; (void)out_size; (void)ws_size;
  const float* q = (const float*)d_in[0];
  const float* k = (const float*)d_in[1];
  const float* v = (const float*)d_in[2];
  const int* mask = (const int*)d_in[3];
  const float* wq = (const float*)d_in[4];
  const float* bq = (const float*)d_in[5];
  const float* wk = (const float*)d_in[6];
  const float* bk = (const float*)d_in[7];
  const float* wv = (const float*)d_in[8];
  const float* bv = (const float*)d_in[9];
  const float* wo = (const float*)d_in[10];
  const float* bo = (const float*)d_in[11];

  u16* attnb = (u16*)d_ws;        // [8192][512] bf16 attention output
  u16* wT = attnb + 4194304;      // 4 x [512][512] bf16 transposed
  u16* qws = wT + 1048576;        // [32 bh][2048][64] bf16, pre-scaled
  u16* kws = qws + 4194304;       // [32 bh][2048][64] bf16
  u16* vTw = kws + 4194304;       // [32 bh][64][2048] bf16 (transposed)
  float* out = (float*)d_out;

  conv_w<<<dim3(8, 8, 4), 256, 0, stream>>>(wq, wk, wv, wo, wT);
  gemm_qkv<<<768, 256, 0, stream>>>(q, k, v, wT, bq, bk, bv, qws, kws, vTw);
  attn_fwd<<<dim3(32, 16), 512, 0, stream>>>(qws, kws, vTw, mask, attnb);
  gemm_out<<<512, 256, 0, stream>>>(attnb, wT + 786432, bo, out);
}